// Round 4
// baseline (901.282 us; speedup 1.0000x reference)
//
#include <hip/hip_runtime.h>

#define NN 100000
#define NTILES 3128   // 32-node work units
#define NE 600000
#define EMB 128

typedef unsigned short u16;
typedef unsigned int u32;
typedef unsigned long long u64;
typedef _Float16 half8 __attribute__((ext_vector_type(8)));
typedef float f32x4 __attribute__((ext_vector_type(4)));

__device__ __forceinline__ float4 ld4(const float* p) { return *(const float4*)p; }
__device__ __forceinline__ void ld8(const float* p, float* o) {
  float4 a = ld4(p), b = ld4(p + 4);
  o[0] = a.x; o[1] = a.y; o[2] = a.z; o[3] = a.w;
  o[4] = b.x; o[5] = b.y; o[6] = b.z; o[7] = b.w;
}
__device__ __forceinline__ u32 packh2(float a, float b) {  // two f32 -> packed f16 pair
  union { _Float16 h[2]; u32 d; } u;
  u.h[0] = (_Float16)a;
  u.h[1] = (_Float16)b;
  return u.d;
}

// ---------------- node embedding init: hb(f16) = emb1[x0] + emb2[x1] ----------------
__global__ __launch_bounds__(256) void node_init_kernel(
    const int* __restrict__ x, const float* __restrict__ emb1,
    const float* __restrict__ emb2, _Float16* __restrict__ hb) {
  int tid = blockIdx.x * blockDim.x + threadIdx.x;
  int n = tid >> 4;
  if (n >= NN) return;
  int kc = tid & 15;
  int x0 = min(max(x[2 * n], 0), 118);
  int x1 = min(max(x[2 * n + 1], 0), 2);  // clip to NUM_CHIR-1
  const float* p1 = emb1 + (size_t)x0 * EMB + kc * 8;
  const float* p2 = emb2 + (size_t)x1 * EMB + kc * 8;
  _Float16 o[8];
#pragma unroll
  for (int j = 0; j < 8; ++j) o[j] = (_Float16)(p1[j] + p2[j]);
  *(ulonglong2*)(hb + (size_t)n * EMB + kc * 8) = *(ulonglong2*)o;
}

// ---------------- CSR build ----------------
__global__ __launch_bounds__(256) void hist_kernel(const int* __restrict__ ei,
                                                   int* __restrict__ deg) {
  int e = blockIdx.x * blockDim.x + threadIdx.x;
  if (e >= NE) return;
  atomicAdd(&deg[ei[NE + e]], 1);
}

__global__ __launch_bounds__(256) void scan1_kernel(const int* __restrict__ deg,
                                                    int* __restrict__ off,
                                                    int* __restrict__ bsum) {
  __shared__ int s[256];
  int t = threadIdx.x;
  int base = blockIdx.x * 1024 + t * 4;
  int v[4];
#pragma unroll
  for (int j = 0; j < 4; ++j) {
    int idx = base + j;
    v[j] = (idx < NN) ? deg[idx] : 0;
  }
  int tsum = v[0] + v[1] + v[2] + v[3];
  s[t] = tsum;
  __syncthreads();
  for (int d = 1; d < 256; d <<= 1) {
    int add = (t >= d) ? s[t - d] : 0;
    __syncthreads();
    s[t] += add;
    __syncthreads();
  }
  int run = s[t] - tsum;
#pragma unroll
  for (int j = 0; j < 4; ++j) {
    int idx = base + j;
    if (idx < NN) off[idx] = run;
    run += v[j];
  }
  if (t == 255) bsum[blockIdx.x] = s[255];
}

__global__ void scan2_kernel(int* __restrict__ bsum, int* __restrict__ off, int nb) {
  if (threadIdx.x == 0) {
    int run = 0;
    for (int b = 0; b < nb; ++b) {
      int v = bsum[b];
      bsum[b] = run;
      run += v;
    }
    off[NN] = run;
  }
}

__global__ __launch_bounds__(256) void scan3_kernel(int* __restrict__ off,
                                                    const int* __restrict__ bsum) {
  int idx = blockIdx.x * blockDim.x + threadIdx.x;
  if (idx < NN) off[idx] += bsum[idx >> 10];
}

__global__ __launch_bounds__(256) void scatter_kernel(
    const int* __restrict__ ei, const int* __restrict__ ea,
    const int* __restrict__ off, int* __restrict__ cnt, int* __restrict__ csr) {
  int e = blockIdx.x * blockDim.x + threadIdx.x;
  if (e >= NE) return;
  int d = ei[NE + e];
  int s = ei[e];
  int a0 = min(max(ea[2 * e], 0), 4);
  int a1 = min(max(ea[2 * e + 1], 0), 2);
  int code = a0 * 3 + a1;  // [0,14]
  int r = atomicAdd(&cnt[d], 1);
  csr[off[d] + r] = s | (code << 20);
}

// combos (f16): cbh[l][code][f] = ee1[l][code/3][f] + ee2[l][code%3][f]
__global__ __launch_bounds__(256) void combo_kernel(const float* __restrict__ ee1,
                                                    const float* __restrict__ ee2,
                                                    _Float16* __restrict__ cbh) {
  int idx = blockIdx.x * blockDim.x + threadIdx.x;
  if (idx >= 5 * 15 * 128) return;
  int l = idx / (15 * 128);
  int rem = idx % (15 * 128);
  int code = rem / 128;
  int f = rem % 128;
  cbh[idx] = (_Float16)(ee1[(l * 5 + code / 3) * 128 + f] + ee2[(l * 3 + code % 3) * 128 + f]);
}

// ---------------- weight prep: 16x16x32-frag-ordered f16 copies of W1/W2 --------------
__global__ __launch_bounds__(256) void prep_w_kernel(
    const float* __restrict__ W1g, const float* __restrict__ W2g,
    _Float16* __restrict__ W1f, _Float16* __restrict__ W2f) {
  int idx = blockIdx.x * blockDim.x + threadIdx.x;
  if (idx >= 40960) return;
  _Float16 o[8];
  if (idx < 20480) {
    int lane = idx & 63;
    int r = idx >> 6;             // l*64 + c*16 + kt*4 + colt
    int nt = r & 3, kt = (r >> 2) & 3, c = (r >> 4) & 3, l = r >> 6;
    int n = c * 64 + nt * 16 + (lane & 15);
    int kb = kt * 32 + (lane >> 4) * 8;
#pragma unroll
    for (int j = 0; j < 8; ++j) o[j] = (_Float16)W1g[((size_t)l * 128 + kb + j) * 256 + n];
    *(ulonglong2*)(W1f + (size_t)idx * 8) = *(ulonglong2*)o;
  } else {
    int i2 = idx - 20480;
    int lane = i2 & 63;
    int r = i2 >> 6;              // l*64 + c*16 + ktl*8 + nt
    int nt = r & 7, ktl = (r >> 3) & 1, c = (r >> 4) & 3, l = r >> 6;
    int n = nt * 16 + (lane & 15);
    int kb = c * 64 + ktl * 32 + (lane >> 4) * 8;
#pragma unroll
    for (int j = 0; j < 8; ++j) o[j] = (_Float16)W2g[((size_t)l * 256 + kb + j) * 128 + n];
    *(ulonglong2*)(W2f + (size_t)i2 * 8) = *(ulonglong2*)o;
  }
}

// ---------------- FUSED agg+mlp v2: no LDS, no barriers, weights from L2 -------------
// 782 blocks x 4 waves; wave (blockIdx*4+w) owns 32-node tile; VGPR-bound occupancy
// (~12-16 waves/CU) so the latency-bound gather has TLP. Weight fragments (64KB/layer,
// shared by all waves) are read straight from global -> L2-resident broadcast.
template <bool NORM>
__global__ __launch_bounds__(256, 3) void fused_kernel(
    const _Float16* __restrict__ hsrc, const float* __restrict__ scsh,
    const int* __restrict__ off, const int* __restrict__ csr,
    const _Float16* __restrict__ cbh, const float* __restrict__ epsp,
    const _Float16* __restrict__ W1f, const _Float16* __restrict__ W2f,
    const float* __restrict__ b1g, const float* __restrict__ b2g,
    _Float16* __restrict__ hout, float* __restrict__ slots) {
  const int t = threadIdx.x;
  const int w = t >> 6;
  const int lane = t & 63;
  const int q = lane >> 4, l15 = lane & 15;
  const int tile = blockIdx.x * 4 + w;
  if (tile >= NTILES) return;
  const int n0 = tile * 32;

  const float eps1 = 1.0f + *epsp;
  const int srcA = ((q & 1) * 2) * 16 + l15;  // quad permutation sources (stage-2 transpose)
  const int srcB = srcA + 16;
  const bool sel = (q >> 1) != 0;

  // per-lane feature-slice constants
  float scv[4][8], shv[4][8];
  if (NORM) {
#pragma unroll
    for (int kt = 0; kt < 4; ++kt) {
      ld8(scsh + kt * 32 + q * 8, scv[kt]);
      ld8(scsh + 128 + kt * 32 + q * 8, shv[kt]);
    }
  }
  half8 c0h[4];
#pragma unroll
  for (int kt = 0; kt < 4; ++kt) c0h[kt] = *(const half8*)(cbh + kt * 32 + q * 8);

  // ---- gather-aggregate both 16-node subtiles into A fragments ----
  half8 nh[2][4];
#pragma unroll
  for (int ntile = 0; ntile < 2; ++ntile) {
    const int node = n0 + ntile * 16 + l15;
    float av[4][8];
#pragma unroll
    for (int kt = 0; kt < 4; ++kt)
#pragma unroll
      for (int j = 0; j < 8; ++j) av[kt][j] = 0.f;
    if (node < NN) {
      half8 sr[4];
#pragma unroll
      for (int kt = 0; kt < 4; ++kt)
        sr[kt] = *(const half8*)(hsrc + (size_t)node * EMB + kt * 32 + q * 8);
#pragma unroll
      for (int kt = 0; kt < 4; ++kt)
#pragma unroll
        for (int j = 0; j < 8; ++j) {
          float hv = (float)sr[kt][j];
          if (NORM) hv = fmaxf(hv * scv[kt][j] + shv[kt][j], 0.f);
          av[kt][j] = eps1 * hv + fmaxf(hv + (float)c0h[kt][j], 0.f);
        }
      const int e1 = off[node + 1];
      int e = off[node];
      for (; e + 1 < e1; e += 2) {  // 2 neighbor chains in flight
        int p0 = csr[e], p1 = csr[e + 1];
        const _Float16* r0p = hsrc + (size_t)(p0 & 0xFFFFF) * EMB;
        const _Float16* r1p = hsrc + (size_t)(p1 & 0xFFFFF) * EMB;
        const _Float16* c0p = cbh + (size_t)(p0 >> 20) * EMB;
        const _Float16* c1p = cbh + (size_t)(p1 >> 20) * EMB;
        half8 r0[4], r1[4], cc0[4], cc1[4];
#pragma unroll
        for (int kt = 0; kt < 4; ++kt) {
          r0[kt] = *(const half8*)(r0p + kt * 32 + q * 8);
          r1[kt] = *(const half8*)(r1p + kt * 32 + q * 8);
          cc0[kt] = *(const half8*)(c0p + kt * 32 + q * 8);
          cc1[kt] = *(const half8*)(c1p + kt * 32 + q * 8);
        }
#pragma unroll
        for (int kt = 0; kt < 4; ++kt)
#pragma unroll
          for (int j = 0; j < 8; ++j) {
            float v0 = (float)r0[kt][j], v1 = (float)r1[kt][j];
            if (NORM) {
              v0 = fmaxf(v0 * scv[kt][j] + shv[kt][j], 0.f);
              v1 = fmaxf(v1 * scv[kt][j] + shv[kt][j], 0.f);
            }
            av[kt][j] += fmaxf(v0 + (float)cc0[kt][j], 0.f);
            av[kt][j] += fmaxf(v1 + (float)cc1[kt][j], 0.f);
          }
      }
      for (; e < e1; ++e) {
        int p0 = csr[e];
        const _Float16* r0p = hsrc + (size_t)(p0 & 0xFFFFF) * EMB;
        const _Float16* c0p = cbh + (size_t)(p0 >> 20) * EMB;
        half8 r0[4], cc0[4];
#pragma unroll
        for (int kt = 0; kt < 4; ++kt) {
          r0[kt] = *(const half8*)(r0p + kt * 32 + q * 8);
          cc0[kt] = *(const half8*)(c0p + kt * 32 + q * 8);
        }
#pragma unroll
        for (int kt = 0; kt < 4; ++kt)
#pragma unroll
          for (int j = 0; j < 8; ++j) {
            float v0 = (float)r0[kt][j];
            if (NORM) v0 = fmaxf(v0 * scv[kt][j] + shv[kt][j], 0.f);
            av[kt][j] += fmaxf(v0 + (float)cc0[kt][j], 0.f);
          }
      }
    }
#pragma unroll
    for (int kt = 0; kt < 4; ++kt) {
      half8 o;
#pragma unroll
      for (int j = 0; j < 8; ++j) o[j] = (_Float16)av[kt][j];
      nh[ntile][kt] = o;
    }
  }

  // ---- GEMM: 16x16x32 core, weight fragments from global (L2-broadcast) ----
  const half8* W1v = (const half8*)W1f;  // frag r at W1v[r*64 + lane]
  const half8* W2v = (const half8*)W2f;

  f32x4 oacc[2][8];
#pragma unroll
  for (int ntile = 0; ntile < 2; ++ntile)
#pragma unroll
    for (int a = 0; a < 8; ++a) oacc[ntile][a] = (f32x4){0.f, 0.f, 0.f, 0.f};

#pragma unroll
  for (int c = 0; c < 4; ++c) {
    f32x4 hacc[2][4];
#pragma unroll
    for (int ntile = 0; ntile < 2; ++ntile)
#pragma unroll
      for (int a = 0; a < 4; ++a) hacc[ntile][a] = (f32x4){0.f, 0.f, 0.f, 0.f};
#pragma unroll
    for (int kt = 0; kt < 4; ++kt) {
#pragma unroll
      for (int colt = 0; colt < 4; ++colt) {
        half8 wh = W1v[(size_t)(c * 16 + kt * 4 + colt) * 64 + lane];
        hacc[0][colt] =
            __builtin_amdgcn_mfma_f32_16x16x32_f16(wh, nh[0][kt], hacc[0][colt], 0, 0, 0);
        hacc[1][colt] =
            __builtin_amdgcn_mfma_f32_16x16x32_f16(wh, nh[1][kt], hacc[1][colt], 0, 0, 0);
      }
    }

    u32 P01[2][4], P23[2][4];
#pragma unroll
    for (int colt = 0; colt < 4; ++colt) {
      float4 b1v = ld4(b1g + c * 64 + colt * 16 + q * 4);
#pragma unroll
      for (int ntile = 0; ntile < 2; ++ntile) {
        float v0 = fmaxf(hacc[ntile][colt][0] + b1v.x, 0.f);
        float v1 = fmaxf(hacc[ntile][colt][1] + b1v.y, 0.f);
        float v2 = fmaxf(hacc[ntile][colt][2] + b1v.z, 0.f);
        float v3 = fmaxf(hacc[ntile][colt][3] + b1v.w, 0.f);
        P01[ntile][colt] = packh2(v0, v1);
        P23[ntile][colt] = packh2(v2, v3);
      }
    }

#pragma unroll
    for (int ktl = 0; ktl < 2; ++ktl) {
      half8 bh[2];
#pragma unroll
      for (int ntile = 0; ntile < 2; ++ntile) {
        union { u32 d[4]; half8 s; } uh;
        int c0 = 2 * ktl, c1 = 2 * ktl + 1;
        u32 a0, a1;
        a0 = (u32)__shfl((int)P01[ntile][c0], srcA);
        a1 = (u32)__shfl((int)P01[ntile][c1], srcA);
        uh.d[0] = sel ? a1 : a0;
        a0 = (u32)__shfl((int)P23[ntile][c0], srcA);
        a1 = (u32)__shfl((int)P23[ntile][c1], srcA);
        uh.d[1] = sel ? a1 : a0;
        a0 = (u32)__shfl((int)P01[ntile][c0], srcB);
        a1 = (u32)__shfl((int)P01[ntile][c1], srcB);
        uh.d[2] = sel ? a1 : a0;
        a0 = (u32)__shfl((int)P23[ntile][c0], srcB);
        a1 = (u32)__shfl((int)P23[ntile][c1], srcB);
        uh.d[3] = sel ? a1 : a0;
        bh[ntile] = uh.s;
      }
#pragma unroll
      for (int nt = 0; nt < 8; ++nt) {
        half8 wh = W2v[(size_t)(c * 16 + ktl * 8 + nt) * 64 + lane];
        oacc[0][nt] = __builtin_amdgcn_mfma_f32_16x16x32_f16(wh, bh[0], oacc[0][nt], 0, 0, 0);
        oacc[1][nt] = __builtin_amdgcn_mfma_f32_16x16x32_f16(wh, bh[1], oacc[1][nt], 0, 0, 0);
      }
    }
  }

  // ---- epilogue: +b2, packed f16 store, BN partials into slot (tile & 31) ----
  float* sums = slots + (size_t)(tile & 31) * 256;
#pragma unroll
  for (int nt = 0; nt < 8; ++nt) {
    int ocb = nt * 16 + q * 4;
    float4 b2v = ld4(b2g + ocb);
    f32x4 s = (f32x4){0.f, 0.f, 0.f, 0.f};
    f32x4 s2 = (f32x4){0.f, 0.f, 0.f, 0.f};
#pragma unroll
    for (int ntile = 0; ntile < 2; ++ntile) {
      int node = n0 + ntile * 16 + l15;
      if (node < NN) {
        float v0 = oacc[ntile][nt][0] + b2v.x;
        float v1 = oacc[ntile][nt][1] + b2v.y;
        float v2 = oacc[ntile][nt][2] + b2v.z;
        float v3 = oacc[ntile][nt][3] + b2v.w;
        u64 pk = (u64)packh2(v0, v1) | ((u64)packh2(v2, v3) << 32);
        *(u64*)(hout + (size_t)node * EMB + ocb) = pk;
        s[0] += v0; s[1] += v1; s[2] += v2; s[3] += v3;
        s2[0] += v0 * v0; s2[1] += v1 * v1; s2[2] += v2 * v2; s2[3] += v3 * v3;
      }
    }
#pragma unroll
    for (int d = 1; d < 16; d <<= 1) {
#pragma unroll
      for (int r = 0; r < 4; ++r) {
        s[r] += __shfl_xor(s[r], d);
        s2[r] += __shfl_xor(s2[r], d);
      }
    }
    if (l15 == 0) {
#pragma unroll
      for (int r = 0; r < 4; ++r) {
        atomicAdd(&sums[ocb + r], s[r]);
        atomicAdd(&sums[128 + ocb + r], s2[r]);
      }
    }
  }
}

// ---------------- stats: reduce 32 slots -> scale/shift (sc, sh) ----------------
__global__ void stats_kernel(const float* __restrict__ slots,
                             const float* __restrict__ gamma,
                             const float* __restrict__ beta,
                             float* __restrict__ scsh) {
  int f = threadIdx.x;  // 128
  float s = 0.f, s2 = 0.f;
#pragma unroll 8
  for (int k = 0; k < 32; ++k) {
    s += slots[k * 256 + f];
    s2 += slots[k * 256 + 128 + f];
  }
  float mean = s * (1.0f / NN);
  float var = s2 * (1.0f / NN) - mean * mean;  // biased
  float sc = gamma[f] * rsqrtf(var + 1e-5f);
  scsh[f] = sc;
  scsh[128 + f] = beta[f] - mean * sc;
}

// ---------------- final output: out = hpre*sc + sh (f32, no relu) ----------------
__global__ __launch_bounds__(256) void out_kernel(
    const _Float16* __restrict__ hpre, const float* __restrict__ scsh,
    float* __restrict__ out) {
  int tid = blockIdx.x * blockDim.x + threadIdx.x;
  int n = tid >> 4;
  if (n >= NN) return;
  int kc = tid & 15;
  ulonglong2 raw = *(const ulonglong2*)(hpre + (size_t)n * EMB + kc * 8);
  _Float16* hr = (_Float16*)&raw;
  float4 sa = ld4(scsh + kc * 8), sb = ld4(scsh + kc * 8 + 4);
  float4 ha = ld4(scsh + 128 + kc * 8), hbv = ld4(scsh + 128 + kc * 8 + 4);
  float scv[8] = {sa.x, sa.y, sa.z, sa.w, sb.x, sb.y, sb.z, sb.w};
  float shv[8] = {ha.x, ha.y, ha.z, ha.w, hbv.x, hbv.y, hbv.z, hbv.w};
  float v[8];
#pragma unroll
  for (int j = 0; j < 8; ++j) v[j] = (float)hr[j] * scv[j] + shv[j];
  float* d = out + (size_t)n * EMB + kc * 8;
  *(float4*)d = make_float4(v[0], v[1], v[2], v[3]);
  *(float4*)(d + 4) = make_float4(v[4], v[5], v[6], v[7]);
}

// ---------------- launch ----------------
extern "C" void kernel_launch(void* const* d_in, const int* in_sizes, int n_in,
                              void* d_out, int out_size, void* d_ws, size_t ws_size,
                              hipStream_t stream) {
  const int* x = (const int*)d_in[0];
  const int* ei = (const int*)d_in[1];
  const int* ea = (const int*)d_in[2];
  const float* x_emb1 = (const float*)d_in[3];
  const float* x_emb2 = (const float*)d_in[4];
  const float* ee1 = (const float*)d_in[5];
  const float* ee2 = (const float*)d_in[6];
  const float* W1 = (const float*)d_in[7];
  const float* b1 = (const float*)d_in[8];
  const float* W2 = (const float*)d_in[9];
  const float* b2 = (const float*)d_in[10];
  const float* eps = (const float*)d_in[11];
  const float* gamma = (const float*)d_in[12];
  const float* beta = (const float*)d_in[13];
  float* out = (float*)d_out;

  // workspace layout (16B-aligned sections)
  float* slots = (float*)d_ws;                  // 5*32*256 BN partial slots
  float* scsh = slots + 5 * 32 * 256;           // 5*256 scale/shift
  _Float16* hp0 = (_Float16*)(scsh + 5 * 256);  // NN*128 f16 (layer out, even layers)
  _Float16* hp1 = hp0 + (size_t)NN * EMB;       // NN*128 f16 (odd layers)
  _Float16* hb = hp1 + (size_t)NN * EMB;        // NN*128 f16 node embeddings
  _Float16* W1f = hb + (size_t)NN * EMB;        // 5*32768 f16
  _Float16* W2f = W1f + 5 * 32768;              // 5*32768 f16
  _Float16* cbh = W2f + 5 * 32768;              // 5*15*128 f16 combos
  int* deg = (int*)(cbh + 5 * 15 * 128);        // NN
  int* off = deg + NN;                          // NN+1
  int* csr = off + NN + 1;                      // NE
  int* bsum = csr + NE;                         // 128

  const int NB_SCAN = (NN + 1023) / 1024;

  // one-time per launch: CSR + combo tables + frag-ordered f16 weights
  hipMemsetAsync(deg, 0, NN * sizeof(int), stream);
  hipMemsetAsync(slots, 0, 5 * 32 * 256 * sizeof(float), stream);
  hist_kernel<<<(NE + 255) / 256, 256, 0, stream>>>(ei, deg);
  scan1_kernel<<<NB_SCAN, 256, 0, stream>>>(deg, off, bsum);
  scan2_kernel<<<1, 64, 0, stream>>>(bsum, off, NB_SCAN);
  scan3_kernel<<<(NN + 255) / 256, 256, 0, stream>>>(off, bsum);
  hipMemsetAsync(deg, 0, NN * sizeof(int), stream);
  scatter_kernel<<<(NE + 255) / 256, 256, 0, stream>>>(ei, ea, off, deg, csr);
  combo_kernel<<<(5 * 15 * 128 + 255) / 256, 256, 0, stream>>>(ee1, ee2, cbh);
  prep_w_kernel<<<160, 256, 0, stream>>>(W1, W2, W1f, W2f);
  node_init_kernel<<<NN * 16 / 256 + 1, 256, 0, stream>>>(x, x_emb1, x_emb2, hb);

  const int FUSED_GRID = (NTILES + 3) / 4;  // 782 blocks x 4 waves (32 nodes each)
  for (int i = 0; i < 5; ++i) {
    _Float16* wr = (i & 1) ? hp1 : hp0;
    if (i == 0)
      fused_kernel<false><<<FUSED_GRID, 256, 0, stream>>>(
          hb, nullptr, off, csr, cbh, eps, W1f, W2f, b1, b2, wr, slots);
    else
      fused_kernel<true><<<FUSED_GRID, 256, 0, stream>>>(
          (i & 1) ? hp0 : hp1, scsh + (size_t)(i - 1) * 256, off, csr,
          cbh + (size_t)i * 15 * EMB, eps + i, W1f + (size_t)i * 32768,
          W2f + (size_t)i * 32768, b1 + (size_t)i * 256, b2 + (size_t)i * 128, wr,
          slots + (size_t)i * 32 * 256);
    stats_kernel<<<1, 128, 0, stream>>>(slots + (size_t)i * 32 * 256,
                                        gamma + (size_t)i * EMB,
                                        beta + (size_t)i * EMB,
                                        scsh + (size_t)i * 256);
  }
  out_kernel<<<NN * 16 / 256 + 1, 256, 0, stream>>>(hp0, scsh + 4 * 256, out);
}

// Round 6
// 673.416 us; speedup vs baseline: 1.3384x; 1.3384x over previous
//
#include <hip/hip_runtime.h>

#define NN 100000
#define NPAD 100096   // 6256 * 16, padded row count for guard-free GEMM
#define NE 600000
#define EMB 128

typedef unsigned short u16;
typedef unsigned int u32;
typedef unsigned long long u64;
typedef _Float16 half8 __attribute__((ext_vector_type(8)));
typedef float f32x4 __attribute__((ext_vector_type(4)));

__device__ __forceinline__ float4 ld4(const float* p) { return *(const float4*)p; }
__device__ __forceinline__ u32 packh2(float a, float b) {  // two f32 -> packed f16 pair
  union { _Float16 h[2]; u32 d; } u;
  u.h[0] = (_Float16)a;
  u.h[1] = (_Float16)b;
  return u.d;
}

// ---------------- node embedding init: hb(f16) = emb1[x0] + emb2[x1] ----------------
__global__ __launch_bounds__(256) void node_init_kernel(
    const int* __restrict__ x, const float* __restrict__ emb1,
    const float* __restrict__ emb2, _Float16* __restrict__ hb) {
  int tid = blockIdx.x * blockDim.x + threadIdx.x;
  int n = tid >> 4;
  if (n >= NN) return;
  int kc = tid & 15;
  int x0 = min(max(x[2 * n], 0), 118);
  int x1 = min(max(x[2 * n + 1], 0), 2);  // x[:,1] sampled 0..118 -> clip to NUM_CHIR-1
  const float* p1 = emb1 + (size_t)x0 * EMB + kc * 8;
  const float* p2 = emb2 + (size_t)x1 * EMB + kc * 8;
  _Float16 o[8];
#pragma unroll
  for (int j = 0; j < 8; ++j) o[j] = (_Float16)(p1[j] + p2[j]);
  *(ulonglong2*)(hb + (size_t)n * EMB + kc * 8) = *(ulonglong2*)o;
}

// ---------------- CSR build ----------------
__global__ __launch_bounds__(256) void hist_kernel(const int* __restrict__ ei,
                                                   int* __restrict__ deg) {
  int e = blockIdx.x * blockDim.x + threadIdx.x;
  if (e >= NE) return;
  atomicAdd(&deg[ei[NE + e]], 1);
}

__global__ __launch_bounds__(256) void scan1_kernel(const int* __restrict__ deg,
                                                    int* __restrict__ off,
                                                    int* __restrict__ bsum) {
  __shared__ int s[256];
  int t = threadIdx.x;
  int base = blockIdx.x * 1024 + t * 4;
  int v[4];
#pragma unroll
  for (int j = 0; j < 4; ++j) {
    int idx = base + j;
    v[j] = (idx < NN) ? deg[idx] : 0;
  }
  int tsum = v[0] + v[1] + v[2] + v[3];
  s[t] = tsum;
  __syncthreads();
  for (int d = 1; d < 256; d <<= 1) {
    int add = (t >= d) ? s[t - d] : 0;
    __syncthreads();
    s[t] += add;
    __syncthreads();
  }
  int run = s[t] - tsum;
#pragma unroll
  for (int j = 0; j < 4; ++j) {
    int idx = base + j;
    if (idx < NN) off[idx] = run;
    run += v[j];
  }
  if (t == 255) bsum[blockIdx.x] = s[255];
}

__global__ void scan2_kernel(int* __restrict__ bsum, int* __restrict__ off, int nb) {
  if (threadIdx.x == 0) {
    int run = 0;
    for (int b = 0; b < nb; ++b) {
      int v = bsum[b];
      bsum[b] = run;
      run += v;
    }
    off[NN] = run;
  }
}

__global__ __launch_bounds__(256) void scan3_kernel(int* __restrict__ off,
                                                    const int* __restrict__ bsum) {
  int idx = blockIdx.x * blockDim.x + threadIdx.x;
  if (idx < NN) off[idx] += bsum[idx >> 10];
}

__global__ __launch_bounds__(256) void scatter_kernel(
    const int* __restrict__ ei, const int* __restrict__ ea,
    const int* __restrict__ off, int* __restrict__ cnt, int* __restrict__ csr) {
  int e = blockIdx.x * blockDim.x + threadIdx.x;
  if (e >= NE) return;
  int d = ei[NE + e];
  int s = ei[e];
  int a0 = min(max(ea[2 * e], 0), 4);
  int a1 = min(max(ea[2 * e + 1], 0), 2);
  int code = a0 * 3 + a1;  // [0,14]
  int r = atomicAdd(&cnt[d], 1);
  csr[off[d] + r] = s | (code << 20);
}

// combos (f16): cbh[l][code][f] = ee1[l][code/3][f] + ee2[l][code%3][f]
__global__ __launch_bounds__(256) void combo_kernel(const float* __restrict__ ee1,
                                                    const float* __restrict__ ee2,
                                                    _Float16* __restrict__ cbh) {
  int idx = blockIdx.x * blockDim.x + threadIdx.x;
  if (idx >= 5 * 15 * 128) return;
  int l = idx / (15 * 128);
  int rem = idx % (15 * 128);
  int code = rem / 128;
  int f = rem % 128;
  cbh[idx] = (_Float16)(ee1[(l * 5 + code / 3) * 128 + f] + ee2[(l * 3 + code % 3) * 128 + f]);
}

// ---------------- weight prep: frag-ordered f16 copies of W1/W2 ----------------
__global__ __launch_bounds__(256) void prep_w_kernel(
    const float* __restrict__ W1g, const float* __restrict__ W2g,
    _Float16* __restrict__ W1f, _Float16* __restrict__ W2f) {
  int idx = blockIdx.x * blockDim.x + threadIdx.x;
  if (idx >= 40960) return;
  _Float16 o[8];
  if (idx < 20480) {
    int lane = idx & 63;
    int r = idx >> 6;             // l*64 + c*16 + kt*4 + colt
    int nt = r & 3, kt = (r >> 2) & 3, c = (r >> 4) & 3, l = r >> 6;
    int n = c * 64 + nt * 16 + (lane & 15);
    int kb = kt * 32 + (lane >> 4) * 8;
#pragma unroll
    for (int j = 0; j < 8; ++j) o[j] = (_Float16)W1g[((size_t)l * 128 + kb + j) * 256 + n];
    *(ulonglong2*)(W1f + (size_t)idx * 8) = *(ulonglong2*)o;
  } else {
    int i2 = idx - 20480;
    int lane = i2 & 63;
    int r = i2 >> 6;              // l*64 + c*16 + ktl*8 + nt
    int nt = r & 7, ktl = (r >> 3) & 1, c = (r >> 4) & 3, l = r >> 6;
    int n = nt * 16 + (lane & 15);
    int kb = c * 64 + ktl * 32 + (lane >> 4) * 8;
#pragma unroll
    for (int j = 0; j < 8; ++j) o[j] = (_Float16)W2g[((size_t)l * 256 + kb + j) * 128 + n];
    *(ulonglong2*)(W2f + (size_t)i2 * 8) = *(ulonglong2*)o;
  }
}

// ---------------- agg: Af = (1+eps)*h + relu(h+c0) + sum relu(h[src]+c) ----------------
// NORM: h = relu(hsrc*sc + sh)  (BN of previous layer fused into the gather).
// Combos are f16 (16B/lane/edge instead of 32B, one load instead of two).
template <bool NORM>
__global__ __launch_bounds__(256) void agg_kernel(
    const _Float16* __restrict__ hsrc, const float* __restrict__ scsh,
    const int* __restrict__ off, const int* __restrict__ csr,
    const _Float16* __restrict__ cbh, const float* __restrict__ epsp,
    _Float16* __restrict__ Af) {
  int tid = blockIdx.x * blockDim.x + threadIdx.x;
  int g = tid >> 4;
  int kc = tid & 15;
  float av[8] = {0.f, 0.f, 0.f, 0.f, 0.f, 0.f, 0.f, 0.f};
  float scv[8], shv[8];
  if (NORM) {
    float4 sa = ld4(scsh + kc * 8), sb = ld4(scsh + kc * 8 + 4);
    float4 ha = ld4(scsh + 128 + kc * 8), hbv = ld4(scsh + 128 + kc * 8 + 4);
    scv[0] = sa.x; scv[1] = sa.y; scv[2] = sa.z; scv[3] = sa.w;
    scv[4] = sb.x; scv[5] = sb.y; scv[6] = sb.z; scv[7] = sb.w;
    shv[0] = ha.x; shv[1] = ha.y; shv[2] = ha.z; shv[3] = ha.w;
    shv[4] = hbv.x; shv[5] = hbv.y; shv[6] = hbv.z; shv[7] = hbv.w;
  }
  if (g < NN) {
    const float eps1 = 1.0f + *epsp;
    ulonglong2 hraw = *(const ulonglong2*)(hsrc + (size_t)g * EMB + kc * 8);
    _Float16* hr = (_Float16*)&hraw;
    half8 c0 = *(const half8*)(cbh + kc * 8);  // self-loop combo (code 0)
#pragma unroll
    for (int j = 0; j < 8; ++j) {
      float hv = (float)hr[j];
      if (NORM) hv = fmaxf(hv * scv[j] + shv[j], 0.f);
      av[j] = eps1 * hv + fmaxf(hv + (float)c0[j], 0.f);
    }
    int s0 = off[g], s1 = off[g + 1];
    int e = s0;
    for (; e + 3 < s1; e += 4) {  // unroll x4: four gather chains in flight
      int p0 = csr[e], p1 = csr[e + 1], p2 = csr[e + 2], p3 = csr[e + 3];
      ulonglong2 r0 = *(const ulonglong2*)(hsrc + (size_t)(p0 & 0xFFFFF) * EMB + kc * 8);
      ulonglong2 r1 = *(const ulonglong2*)(hsrc + (size_t)(p1 & 0xFFFFF) * EMB + kc * 8);
      ulonglong2 r2 = *(const ulonglong2*)(hsrc + (size_t)(p2 & 0xFFFFF) * EMB + kc * 8);
      ulonglong2 r3 = *(const ulonglong2*)(hsrc + (size_t)(p3 & 0xFFFFF) * EMB + kc * 8);
      ulonglong2 rr[4] = {r0, r1, r2, r3};
      int pp[4] = {p0, p1, p2, p3};
#pragma unroll
      for (int u = 0; u < 4; ++u) {
        half8 cc = *(const half8*)(cbh + (size_t)(pp[u] >> 20) * EMB + kc * 8);
        _Float16* sp = (_Float16*)&rr[u];
#pragma unroll
        for (int j = 0; j < 8; ++j) {
          float v = (float)sp[j];
          if (NORM) v = fmaxf(v * scv[j] + shv[j], 0.f);
          av[j] += fmaxf(v + (float)cc[j], 0.f);
        }
      }
    }
    for (; e < s1; ++e) {
      int p0 = csr[e];
      ulonglong2 r0 = *(const ulonglong2*)(hsrc + (size_t)(p0 & 0xFFFFF) * EMB + kc * 8);
      half8 cc = *(const half8*)(cbh + (size_t)(p0 >> 20) * EMB + kc * 8);
      _Float16* sp = (_Float16*)&r0;
#pragma unroll
      for (int j = 0; j < 8; ++j) {
        float v = (float)sp[j];
        if (NORM) v = fmaxf(v * scv[j] + shv[j], 0.f);
        av[j] += fmaxf(v + (float)cc[j], 0.f);
      }
    }
  }
  _Float16 o[8];
#pragma unroll
  for (int j = 0; j < 8; ++j) o[j] = (_Float16)av[j];
  *(ulonglong2*)(Af + (size_t)g * EMB + kc * 8) = *(ulonglong2*)o;  // zeros for pad rows
}

// ---------------- mlp: EXACT R0 structure (16KB Ws, 4-barrier, pack overlaps W2 staging) ----
__global__ __launch_bounds__(256, 4) void mlp_kernel(
    const _Float16* __restrict__ Af, const _Float16* __restrict__ W1f,
    const _Float16* __restrict__ W2f,
    const float* __restrict__ b1g, const float* __restrict__ b2g,
    _Float16* __restrict__ hpre, float* __restrict__ slots) {
  __shared__ __align__(16) _Float16 Ws[16 * 64 * 8];  // 16KB, W1 then W2 per chunk

  const int t = threadIdx.x;
  const int w = t >> 6;
  const int lane = t & 63;
  const int q = lane >> 4, l15 = lane & 15;
  const int gw = blockIdx.x * 4 + w;   // global wave id, 0..6255
  const int n0 = gw * 16;              // 16 nodes per wave
  float* sums = slots + (size_t)(gw & 31) * 256;

  // ---- A fragments loaded ONCE, held across all chunks ----
  half8 nh[4];
#pragma unroll
  for (int kt = 0; kt < 4; ++kt)
    nh[kt] = *(const half8*)(Af + (size_t)(n0 + l15) * EMB + kt * 32 + q * 8);

  f32x4 oacc[8];  // [out col tile]
#pragma unroll
  for (int a = 0; a < 8; ++a) oacc[a] = (f32x4){0.f, 0.f, 0.f, 0.f};

  const int srcA = ((q & 1) * 2) * 16 + l15;  // quad permutation sources
  const int srcB = srcA + 16;
  const bool sel = (q >> 1) != 0;

  for (int c = 0; c < 4; ++c) {
    __syncthreads();  // prev chunk's stage-2 LDS reads complete
    // ---- stage W1 chunk c (wave w covers frags w*4..w*4+3) ----
    {
      const _Float16* gb = W1f + ((size_t)(c * 16 + w * 4) * 64 + lane) * 8;
#pragma unroll
      for (int j = 0; j < 4; ++j)
        *(ulonglong2*)&Ws[(w * 4 + j) * 512 + lane * 8] =
            *(const ulonglong2*)(gb + (size_t)j * 512);
    }
    __syncthreads();

    // ---- stage 1: hmidT[col c*64+colt*16+q*4+r][node l15] ----
    f32x4 hacc[4];
#pragma unroll
    for (int a = 0; a < 4; ++a) hacc[a] = (f32x4){0.f, 0.f, 0.f, 0.f};
#pragma unroll
    for (int kt = 0; kt < 4; ++kt) {
#pragma unroll
      for (int colt = 0; colt < 4; ++colt) {
        half8 wh = *(const half8*)&Ws[(kt * 4 + colt) * 512 + lane * 8];
        hacc[colt] = __builtin_amdgcn_mfma_f32_16x16x32_f16(wh, nh[kt], hacc[colt], 0, 0, 0);
      }
    }
    __syncthreads();  // stage-1 LDS reads complete; buffer reusable

    // ---- stage W2 chunk c ----
    {
      const _Float16* gb = W2f + ((size_t)(c * 16 + w * 4) * 64 + lane) * 8;
#pragma unroll
      for (int j = 0; j < 4; ++j)
        *(ulonglong2*)&Ws[(w * 4 + j) * 512 + lane * 8] =
            *(const ulonglong2*)(gb + (size_t)j * 512);
    }

    // ---- bias + relu + pack to f16 pairs (overlaps staging) ----
    u32 P01[4], P23[4];  // [colt]
#pragma unroll
    for (int colt = 0; colt < 4; ++colt) {
      float4 b1v = ld4(b1g + c * 64 + colt * 16 + q * 4);
      float v0 = fmaxf(hacc[colt][0] + b1v.x, 0.f);
      float v1 = fmaxf(hacc[colt][1] + b1v.y, 0.f);
      float v2 = fmaxf(hacc[colt][2] + b1v.z, 0.f);
      float v3 = fmaxf(hacc[colt][3] + b1v.w, 0.f);
      P01[colt] = packh2(v0, v1);
      P23[colt] = packh2(v2, v3);
    }
    __syncthreads();  // W2 staged

    // ---- stage 2: quad-permute hmid into B-frags, multiply with W2 from LDS ----
#pragma unroll
    for (int ktl = 0; ktl < 2; ++ktl) {
      half8 bh;
      {
        union { u32 d[4]; half8 s; } uh;
        int c0 = 2 * ktl, c1 = 2 * ktl + 1;
        u32 a0, a1;
        a0 = (u32)__shfl((int)P01[c0], srcA); a1 = (u32)__shfl((int)P01[c1], srcA);
        uh.d[0] = sel ? a1 : a0;
        a0 = (u32)__shfl((int)P23[c0], srcA); a1 = (u32)__shfl((int)P23[c1], srcA);
        uh.d[1] = sel ? a1 : a0;
        a0 = (u32)__shfl((int)P01[c0], srcB); a1 = (u32)__shfl((int)P01[c1], srcB);
        uh.d[2] = sel ? a1 : a0;
        a0 = (u32)__shfl((int)P23[c0], srcB); a1 = (u32)__shfl((int)P23[c1], srcB);
        uh.d[3] = sel ? a1 : a0;
        bh = uh.s;
      }
#pragma unroll
      for (int nt = 0; nt < 8; ++nt) {
        half8 wh = *(const half8*)&Ws[(ktl * 8 + nt) * 512 + lane * 8];
        oacc[nt] = __builtin_amdgcn_mfma_f32_16x16x32_f16(wh, bh, oacc[nt], 0, 0, 0);
      }
    }
  }

  // ---- epilogue: +b2, packed f16 store (8B), BN partials into slot ----
  const int node = n0 + l15;
#pragma unroll
  for (int nt = 0; nt < 8; ++nt) {
    int ocb = nt * 16 + q * 4;  // 4 consecutive out cols per lane
    float4 b2v = ld4(b2g + ocb);
    f32x4 s = (f32x4){0.f, 0.f, 0.f, 0.f};
    f32x4 s2 = (f32x4){0.f, 0.f, 0.f, 0.f};
    if (node < NN) {
      float v0 = oacc[nt][0] + b2v.x;
      float v1 = oacc[nt][1] + b2v.y;
      float v2 = oacc[nt][2] + b2v.z;
      float v3 = oacc[nt][3] + b2v.w;
      u64 pk = (u64)packh2(v0, v1) | ((u64)packh2(v2, v3) << 32);
      *(u64*)(hpre + (size_t)node * EMB + ocb) = pk;
      s[0] = v0; s[1] = v1; s[2] = v2; s[3] = v3;
      s2[0] = v0 * v0; s2[1] = v1 * v1; s2[2] = v2 * v2; s2[3] = v3 * v3;
    }
#pragma unroll
    for (int d = 1; d < 16; d <<= 1) {
#pragma unroll
      for (int r = 0; r < 4; ++r) {
        s[r] += __shfl_xor(s[r], d);
        s2[r] += __shfl_xor(s2[r], d);
      }
    }
    if (l15 == 0) {
#pragma unroll
      for (int r = 0; r < 4; ++r) {
        atomicAdd(&sums[ocb + r], s[r]);
        atomicAdd(&sums[128 + ocb + r], s2[r]);
      }
    }
  }
}

// ---------------- stats: reduce 32 slots -> scale/shift (sc, sh) ----------------
__global__ void stats_kernel(const float* __restrict__ slots,
                             const float* __restrict__ gamma,
                             const float* __restrict__ beta,
                             float* __restrict__ scsh) {
  int f = threadIdx.x;  // 128
  float s = 0.f, s2 = 0.f;
#pragma unroll 8
  for (int k = 0; k < 32; ++k) {
    s += slots[k * 256 + f];
    s2 += slots[k * 256 + 128 + f];
  }
  float mean = s * (1.0f / NN);
  float var = s2 * (1.0f / NN) - mean * mean;  // biased
  float sc = gamma[f] * rsqrtf(var + 1e-5f);
  scsh[f] = sc;
  scsh[128 + f] = beta[f] - mean * sc;
}

// ---------------- final output: out = hpre*sc + sh (f32, no relu) ----------------
__global__ __launch_bounds__(256) void out_kernel(
    const _Float16* __restrict__ hpre, const float* __restrict__ scsh,
    float* __restrict__ out) {
  int tid = blockIdx.x * blockDim.x + threadIdx.x;
  int n = tid >> 4;
  if (n >= NN) return;
  int kc = tid & 15;
  ulonglong2 raw = *(const ulonglong2*)(hpre + (size_t)n * EMB + kc * 8);
  _Float16* hr = (_Float16*)&raw;
  float4 sa = ld4(scsh + kc * 8), sb = ld4(scsh + kc * 8 + 4);
  float4 ha = ld4(scsh + 128 + kc * 8), hbv = ld4(scsh + 128 + kc * 8 + 4);
  float scv[8] = {sa.x, sa.y, sa.z, sa.w, sb.x, sb.y, sb.z, sb.w};
  float shv[8] = {ha.x, ha.y, ha.z, ha.w, hbv.x, hbv.y, hbv.z, hbv.w};
  float v[8];
#pragma unroll
  for (int j = 0; j < 8; ++j) v[j] = (float)hr[j] * scv[j] + shv[j];
  float* d = out + (size_t)n * EMB + kc * 8;
  *(float4*)d = make_float4(v[0], v[1], v[2], v[3]);
  *(float4*)(d + 4) = make_float4(v[4], v[5], v[6], v[7]);
}

// ---------------- launch ----------------
extern "C" void kernel_launch(void* const* d_in, const int* in_sizes, int n_in,
                              void* d_out, int out_size, void* d_ws, size_t ws_size,
                              hipStream_t stream) {
  const int* x = (const int*)d_in[0];
  const int* ei = (const int*)d_in[1];
  const int* ea = (const int*)d_in[2];
  const float* x_emb1 = (const float*)d_in[3];
  const float* x_emb2 = (const float*)d_in[4];
  const float* ee1 = (const float*)d_in[5];
  const float* ee2 = (const float*)d_in[6];
  const float* W1 = (const float*)d_in[7];
  const float* b1 = (const float*)d_in[8];
  const float* W2 = (const float*)d_in[9];
  const float* b2 = (const float*)d_in[10];
  const float* eps = (const float*)d_in[11];
  const float* gamma = (const float*)d_in[12];
  const float* beta = (const float*)d_in[13];
  float* out = (float*)d_out;

  // workspace layout (16B-aligned sections)
  float* slots = (float*)d_ws;                  // 5*32*256 BN partial slots
  float* scsh = slots + 5 * 32 * 256;           // 5*256 scale/shift
  _Float16* hpre = (_Float16*)(scsh + 5 * 256); // NN*128 f16
  _Float16* Af = hpre + (size_t)NN * EMB;       // NPAD*128 f16
  _Float16* hb = Af + (size_t)NPAD * EMB;       // NN*128 f16
  _Float16* W1f = hb + (size_t)NN * EMB;        // 5*32768 f16
  _Float16* W2f = W1f + 5 * 32768;              // 5*32768 f16
  _Float16* cbh = W2f + 5 * 32768;              // 5*15*128 f16 combos
  int* deg = (int*)(cbh + 5 * 15 * 128 + 64);   // NN (pad to 16B boundary)
  int* off = deg + NN;                          // NN+1
  int* csr = off + NN + 1;                      // NE
  int* bsum = csr + NE;                         // 128

  const int NB_SCAN = (NN + 1023) / 1024;

  // one-time per launch: CSR + combo tables + frag-ordered f16 weights
  hipMemsetAsync(deg, 0, NN * sizeof(int), stream);
  hipMemsetAsync(slots, 0, 5 * 32 * 256 * sizeof(float), stream);
  hist_kernel<<<(NE + 255) / 256, 256, 0, stream>>>(ei, deg);
  scan1_kernel<<<NB_SCAN, 256, 0, stream>>>(deg, off, bsum);
  scan2_kernel<<<1, 64, 0, stream>>>(bsum, off, NB_SCAN);
  scan3_kernel<<<(NN + 255) / 256, 256, 0, stream>>>(off, bsum);
  hipMemsetAsync(deg, 0, NN * sizeof(int), stream);
  scatter_kernel<<<(NE + 255) / 256, 256, 0, stream>>>(ei, ea, off, deg, csr);
  combo_kernel<<<(5 * 15 * 128 + 255) / 256, 256, 0, stream>>>(ee1, ee2, cbh);
  prep_w_kernel<<<160, 256, 0, stream>>>(W1, W2, W1f, W2f);
  node_init_kernel<<<NN * 16 / 256 + 1, 256, 0, stream>>>(x, x_emb1, x_emb2, hb);

  const int NBLK = NPAD / 64;  // 1564 blocks x 4 waves (16 nodes each)
  for (int i = 0; i < 5; ++i) {
    if (i == 0)
      agg_kernel<false><<<NPAD * 16 / 256, 256, 0, stream>>>(
          hb, nullptr, off, csr, cbh + (size_t)i * 15 * EMB, eps + i, Af);
    else
      agg_kernel<true><<<NPAD * 16 / 256, 256, 0, stream>>>(
          hpre, scsh + (size_t)(i - 1) * 256, off, csr,
          cbh + (size_t)i * 15 * EMB, eps + i, Af);
    mlp_kernel<<<NBLK, 256, 0, stream>>>(
        Af, W1f + (size_t)i * 32768, W2f + (size_t)i * 32768,
        b1 + (size_t)i * 256, b2 + (size_t)i * 128, hpre,
        slots + (size_t)i * 32 * 256);
    stats_kernel<<<1, 128, 0, stream>>>(slots + (size_t)i * 32 * 256,
                                        gamma + (size_t)i * EMB,
                                        beta + (size_t)i * EMB,
                                        scsh + (size_t)i * 256);
  }
  out_kernel<<<NN * 16 / 256 + 1, 256, 0, stream>>>(hpre, scsh + 4 * 256, out);
}

// Round 7
// 644.090 us; speedup vs baseline: 1.3993x; 1.0455x over previous
//
#include <hip/hip_runtime.h>

#define NN 100000
#define NPAD 100096   // 6256 * 16, padded row count for guard-free GEMM
#define NE 600000
#define EMB 128

typedef unsigned short u16;
typedef unsigned int u32;
typedef unsigned long long u64;
typedef _Float16 half8 __attribute__((ext_vector_type(8)));
typedef float f32x4 __attribute__((ext_vector_type(4)));

__device__ __forceinline__ float4 ld4(const float* p) { return *(const float4*)p; }
__device__ __forceinline__ u32 packh2(float a, float b) {  // two f32 -> packed f16 pair
  union { _Float16 h[2]; u32 d; } u;
  u.h[0] = (_Float16)a;
  u.h[1] = (_Float16)b;
  return u.d;
}

// ---------------- node embedding init: hb(f16) = emb1[x0] + emb2[x1] ----------------
__global__ __launch_bounds__(256) void node_init_kernel(
    const int* __restrict__ x, const float* __restrict__ emb1,
    const float* __restrict__ emb2, _Float16* __restrict__ hb) {
  int tid = blockIdx.x * blockDim.x + threadIdx.x;
  int n = tid >> 4;
  if (n >= NN) return;
  int kc = tid & 15;
  int x0 = min(max(x[2 * n], 0), 118);
  int x1 = min(max(x[2 * n + 1], 0), 2);  // x[:,1] sampled 0..118 -> clip to NUM_CHIR-1
  const float* p1 = emb1 + (size_t)x0 * EMB + kc * 8;
  const float* p2 = emb2 + (size_t)x1 * EMB + kc * 8;
  _Float16 o[8];
#pragma unroll
  for (int j = 0; j < 8; ++j) o[j] = (_Float16)(p1[j] + p2[j]);
  *(ulonglong2*)(hb + (size_t)n * EMB + kc * 8) = *(ulonglong2*)o;
}

// ---------------- CSR build ----------------
__global__ __launch_bounds__(256) void hist_kernel(const int* __restrict__ ei,
                                                   int* __restrict__ deg) {
  int e = blockIdx.x * blockDim.x + threadIdx.x;
  if (e >= NE) return;
  atomicAdd(&deg[ei[NE + e]], 1);
}

__global__ __launch_bounds__(256) void scan1_kernel(const int* __restrict__ deg,
                                                    int* __restrict__ off,
                                                    int* __restrict__ bsum) {
  __shared__ int s[256];
  int t = threadIdx.x;
  int base = blockIdx.x * 1024 + t * 4;
  int v[4];
#pragma unroll
  for (int j = 0; j < 4; ++j) {
    int idx = base + j;
    v[j] = (idx < NN) ? deg[idx] : 0;
  }
  int tsum = v[0] + v[1] + v[2] + v[3];
  s[t] = tsum;
  __syncthreads();
  for (int d = 1; d < 256; d <<= 1) {
    int add = (t >= d) ? s[t - d] : 0;
    __syncthreads();
    s[t] += add;
    __syncthreads();
  }
  int run = s[t] - tsum;
#pragma unroll
  for (int j = 0; j < 4; ++j) {
    int idx = base + j;
    if (idx < NN) off[idx] = run;
    run += v[j];
  }
  if (t == 255) bsum[blockIdx.x] = s[255];
}

// wave prefix-scan over <=128 block sums (replaces the serial 1-thread loop)
__global__ void scan2_kernel(int* __restrict__ bsum, int* __restrict__ off, int nb) {
  int lane = threadIdx.x;  // 64 threads
  int v0 = (lane < nb) ? bsum[lane] : 0;
  int v1 = (lane + 64 < nb) ? bsum[lane + 64] : 0;
  int s0 = v0, s1 = v1;
  for (int d = 1; d < 64; d <<= 1) {
    int t0 = __shfl_up(s0, d);
    int t1 = __shfl_up(s1, d);
    if (lane >= d) { s0 += t0; s1 += t1; }
  }
  int tot0 = __shfl(s0, 63);
  int tot1 = __shfl(s1, 63);
  if (lane < nb) bsum[lane] = s0 - v0;                 // exclusive prefix
  if (lane + 64 < nb) bsum[lane + 64] = tot0 + s1 - v1;
  if (lane == 0) off[NN] = tot0 + tot1;
}

__global__ __launch_bounds__(256) void scan3_kernel(int* __restrict__ off,
                                                    const int* __restrict__ bsum) {
  int idx = blockIdx.x * blockDim.x + threadIdx.x;
  if (idx < NN) off[idx] += bsum[idx >> 10];
}

__global__ __launch_bounds__(256) void scatter_kernel(
    const int* __restrict__ ei, const int* __restrict__ ea,
    const int* __restrict__ off, int* __restrict__ cnt, int* __restrict__ csr) {
  int e = blockIdx.x * blockDim.x + threadIdx.x;
  if (e >= NE) return;
  int d = ei[NE + e];
  int s = ei[e];
  int a0 = min(max(ea[2 * e], 0), 4);
  int a1 = min(max(ea[2 * e + 1], 0), 2);
  int code = a0 * 3 + a1;  // [0,14]
  int r = atomicAdd(&cnt[d], 1);
  csr[off[d] + r] = s | (code << 20);
}

// ---------------- degree-bucket permutation (counting sort, DESCENDING degree) -------
// Waves in agg then own 4 equal-degree nodes: no max-vs-mean divergence waste, and
// heavy blocks launch first (LPT scheduling).
__global__ __launch_bounds__(256) void dhist_kernel(const int* __restrict__ deg,
                                                    int* __restrict__ gbins) {
  __shared__ int l[33];
  int t = threadIdx.x;
  if (t < 33) l[t] = 0;
  __syncthreads();
  int n = blockIdx.x * 256 + t;
  if (n < NN) atomicAdd(&l[32 - min(deg[n], 32)], 1);
  __syncthreads();
  if (t < 33 && l[t]) atomicAdd(&gbins[t], l[t]);
}

__global__ void dscan_kernel(int* __restrict__ gbins) {
  int lane = threadIdx.x;  // 64
  int v = (lane < 33) ? gbins[lane] : 0;
  int s = v;
  for (int d = 1; d < 64; d <<= 1) {
    int t = __shfl_up(s, d);
    if (lane >= d) s += t;
  }
  if (lane < 33) gbins[lane] = s - v;  // exclusive bin starts
}

__global__ __launch_bounds__(256) void dscatter_kernel(const int* __restrict__ deg,
                                                       int* __restrict__ gbins,
                                                       int* __restrict__ perm) {
  __shared__ int lcnt[33], lbase[33];
  int t = threadIdx.x;
  if (t < 33) lcnt[t] = 0;
  __syncthreads();
  int n = blockIdx.x * 256 + t;
  int b = 0, r = 0;
  if (n < NN) {
    b = 32 - min(deg[n], 32);
    r = atomicAdd(&lcnt[b], 1);
  }
  __syncthreads();
  if (t < 33) lbase[t] = lcnt[t] ? atomicAdd(&gbins[t], lcnt[t]) : 0;
  __syncthreads();
  if (n < NN) perm[lbase[b] + r] = n;
}

// combos (f16): cbh[l][code][f] = ee1[l][code/3][f] + ee2[l][code%3][f]
__global__ __launch_bounds__(256) void combo_kernel(const float* __restrict__ ee1,
                                                    const float* __restrict__ ee2,
                                                    _Float16* __restrict__ cbh) {
  int idx = blockIdx.x * blockDim.x + threadIdx.x;
  if (idx >= 5 * 15 * 128) return;
  int l = idx / (15 * 128);
  int rem = idx % (15 * 128);
  int code = rem / 128;
  int f = rem % 128;
  cbh[idx] = (_Float16)(ee1[(l * 5 + code / 3) * 128 + f] + ee2[(l * 3 + code % 3) * 128 + f]);
}

// ---------------- weight prep: frag-ordered f16 copies of W1/W2 ----------------
__global__ __launch_bounds__(256) void prep_w_kernel(
    const float* __restrict__ W1g, const float* __restrict__ W2g,
    _Float16* __restrict__ W1f, _Float16* __restrict__ W2f) {
  int idx = blockIdx.x * blockDim.x + threadIdx.x;
  if (idx >= 40960) return;
  _Float16 o[8];
  if (idx < 20480) {
    int lane = idx & 63;
    int r = idx >> 6;             // l*64 + c*16 + kt*4 + colt
    int nt = r & 3, kt = (r >> 2) & 3, c = (r >> 4) & 3, l = r >> 6;
    int n = c * 64 + nt * 16 + (lane & 15);
    int kb = kt * 32 + (lane >> 4) * 8;
#pragma unroll
    for (int j = 0; j < 8; ++j) o[j] = (_Float16)W1g[((size_t)l * 128 + kb + j) * 256 + n];
    *(ulonglong2*)(W1f + (size_t)idx * 8) = *(ulonglong2*)o;
  } else {
    int i2 = idx - 20480;
    int lane = i2 & 63;
    int r = i2 >> 6;              // l*64 + c*16 + ktl*8 + nt
    int nt = r & 7, ktl = (r >> 3) & 1, c = (r >> 4) & 3, l = r >> 6;
    int n = nt * 16 + (lane & 15);
    int kb = c * 64 + ktl * 32 + (lane >> 4) * 8;
#pragma unroll
    for (int j = 0; j < 8; ++j) o[j] = (_Float16)W2g[((size_t)l * 256 + kb + j) * 128 + n];
    *(ulonglong2*)(W2f + (size_t)i2 * 8) = *(ulonglong2*)o;
  }
}

// ---------------- agg: Af = (1+eps)*h + relu(h+c0) + sum relu(h[src]+c) ----------------
// NORM: h = relu(hsrc*sc + sh). Nodes are processed in degree-sorted order via perm:
// the 4 nodes of a wave have equal degree -> no idle-lane iterations in the edge loop.
template <bool NORM>
__global__ __launch_bounds__(256) void agg_kernel(
    const _Float16* __restrict__ hsrc, const float* __restrict__ scsh,
    const int* __restrict__ off, const int* __restrict__ csr,
    const _Float16* __restrict__ cbh, const float* __restrict__ epsp,
    const int* __restrict__ perm, _Float16* __restrict__ Af) {
  int tid = blockIdx.x * blockDim.x + threadIdx.x;
  int g = tid >> 4;
  int kc = tid & 15;
  float av[8] = {0.f, 0.f, 0.f, 0.f, 0.f, 0.f, 0.f, 0.f};
  float scv[8], shv[8];
  if (NORM) {
    float4 sa = ld4(scsh + kc * 8), sb = ld4(scsh + kc * 8 + 4);
    float4 ha = ld4(scsh + 128 + kc * 8), hbv = ld4(scsh + 128 + kc * 8 + 4);
    scv[0] = sa.x; scv[1] = sa.y; scv[2] = sa.z; scv[3] = sa.w;
    scv[4] = sb.x; scv[5] = sb.y; scv[6] = sb.z; scv[7] = sb.w;
    shv[0] = ha.x; shv[1] = ha.y; shv[2] = ha.z; shv[3] = ha.w;
    shv[4] = hbv.x; shv[5] = hbv.y; shv[6] = hbv.z; shv[7] = hbv.w;
  }
  int node = g;  // pad rows keep identity (write zeros)
  if (g < NN) {
    node = perm[g];
    const float eps1 = 1.0f + *epsp;
    ulonglong2 hraw = *(const ulonglong2*)(hsrc + (size_t)node * EMB + kc * 8);
    _Float16* hr = (_Float16*)&hraw;
    half8 c0 = *(const half8*)(cbh + kc * 8);  // self-loop combo (code 0)
#pragma unroll
    for (int j = 0; j < 8; ++j) {
      float hv = (float)hr[j];
      if (NORM) hv = fmaxf(hv * scv[j] + shv[j], 0.f);
      av[j] = eps1 * hv + fmaxf(hv + (float)c0[j], 0.f);
    }
    int s0 = off[node], s1 = off[node + 1];
    int e = s0;
    for (; e + 3 < s1; e += 4) {  // unroll x4: four gather chains in flight
      int p0 = csr[e], p1 = csr[e + 1], p2 = csr[e + 2], p3 = csr[e + 3];
      ulonglong2 r0 = *(const ulonglong2*)(hsrc + (size_t)(p0 & 0xFFFFF) * EMB + kc * 8);
      ulonglong2 r1 = *(const ulonglong2*)(hsrc + (size_t)(p1 & 0xFFFFF) * EMB + kc * 8);
      ulonglong2 r2 = *(const ulonglong2*)(hsrc + (size_t)(p2 & 0xFFFFF) * EMB + kc * 8);
      ulonglong2 r3 = *(const ulonglong2*)(hsrc + (size_t)(p3 & 0xFFFFF) * EMB + kc * 8);
      ulonglong2 rr[4] = {r0, r1, r2, r3};
      int pp[4] = {p0, p1, p2, p3};
#pragma unroll
      for (int u = 0; u < 4; ++u) {
        half8 cc = *(const half8*)(cbh + (size_t)(pp[u] >> 20) * EMB + kc * 8);
        _Float16* sp = (_Float16*)&rr[u];
#pragma unroll
        for (int j = 0; j < 8; ++j) {
          float v = (float)sp[j];
          if (NORM) v = fmaxf(v * scv[j] + shv[j], 0.f);
          av[j] += fmaxf(v + (float)cc[j], 0.f);
        }
      }
    }
    for (; e < s1; ++e) {
      int p0 = csr[e];
      ulonglong2 r0 = *(const ulonglong2*)(hsrc + (size_t)(p0 & 0xFFFFF) * EMB + kc * 8);
      half8 cc = *(const half8*)(cbh + (size_t)(p0 >> 20) * EMB + kc * 8);
      _Float16* sp = (_Float16*)&r0;
#pragma unroll
      for (int j = 0; j < 8; ++j) {
        float v = (float)sp[j];
        if (NORM) v = fmaxf(v * scv[j] + shv[j], 0.f);
        av[j] += fmaxf(v + (float)cc[j], 0.f);
      }
    }
  }
  _Float16 o[8];
#pragma unroll
  for (int j = 0; j < 8; ++j) o[j] = (_Float16)av[j];
  *(ulonglong2*)(Af + (size_t)node * EMB + kc * 8) = *(ulonglong2*)o;
}

// ---------------- mlp: EXACT R0 structure (16KB Ws, 4-barrier, pack overlaps W2 staging) ----
__global__ __launch_bounds__(256, 4) void mlp_kernel(
    const _Float16* __restrict__ Af, const _Float16* __restrict__ W1f,
    const _Float16* __restrict__ W2f,
    const float* __restrict__ b1g, const float* __restrict__ b2g,
    _Float16* __restrict__ hpre, float* __restrict__ slots) {
  __shared__ __align__(16) _Float16 Ws[16 * 64 * 8];  // 16KB, W1 then W2 per chunk

  const int t = threadIdx.x;
  const int w = t >> 6;
  const int lane = t & 63;
  const int q = lane >> 4, l15 = lane & 15;
  const int gw = blockIdx.x * 4 + w;   // global wave id, 0..6255
  const int n0 = gw * 16;              // 16 nodes per wave
  float* sums = slots + (size_t)(gw & 31) * 256;

  // ---- A fragments loaded ONCE, held across all chunks ----
  half8 nh[4];
#pragma unroll
  for (int kt = 0; kt < 4; ++kt)
    nh[kt] = *(const half8*)(Af + (size_t)(n0 + l15) * EMB + kt * 32 + q * 8);

  f32x4 oacc[8];  // [out col tile]
#pragma unroll
  for (int a = 0; a < 8; ++a) oacc[a] = (f32x4){0.f, 0.f, 0.f, 0.f};

  const int srcA = ((q & 1) * 2) * 16 + l15;  // quad permutation sources
  const int srcB = srcA + 16;
  const bool sel = (q >> 1) != 0;

  for (int c = 0; c < 4; ++c) {
    __syncthreads();  // prev chunk's stage-2 LDS reads complete
    // ---- stage W1 chunk c (wave w covers frags w*4..w*4+3) ----
    {
      const _Float16* gb = W1f + ((size_t)(c * 16 + w * 4) * 64 + lane) * 8;
#pragma unroll
      for (int j = 0; j < 4; ++j)
        *(ulonglong2*)&Ws[(w * 4 + j) * 512 + lane * 8] =
            *(const ulonglong2*)(gb + (size_t)j * 512);
    }
    __syncthreads();

    // ---- stage 1: hmidT[col c*64+colt*16+q*4+r][node l15] ----
    f32x4 hacc[4];
#pragma unroll
    for (int a = 0; a < 4; ++a) hacc[a] = (f32x4){0.f, 0.f, 0.f, 0.f};
#pragma unroll
    for (int kt = 0; kt < 4; ++kt) {
#pragma unroll
      for (int colt = 0; colt < 4; ++colt) {
        half8 wh = *(const half8*)&Ws[(kt * 4 + colt) * 512 + lane * 8];
        hacc[colt] = __builtin_amdgcn_mfma_f32_16x16x32_f16(wh, nh[kt], hacc[colt], 0, 0, 0);
      }
    }
    __syncthreads();  // stage-1 LDS reads complete; buffer reusable

    // ---- stage W2 chunk c ----
    {
      const _Float16* gb = W2f + ((size_t)(c * 16 + w * 4) * 64 + lane) * 8;
#pragma unroll
      for (int j = 0; j < 4; ++j)
        *(ulonglong2*)&Ws[(w * 4 + j) * 512 + lane * 8] =
            *(const ulonglong2*)(gb + (size_t)j * 512);
    }

    // ---- bias + relu + pack to f16 pairs (overlaps staging) ----
    u32 P01[4], P23[4];  // [colt]
#pragma unroll
    for (int colt = 0; colt < 4; ++colt) {
      float4 b1v = ld4(b1g + c * 64 + colt * 16 + q * 4);
      float v0 = fmaxf(hacc[colt][0] + b1v.x, 0.f);
      float v1 = fmaxf(hacc[colt][1] + b1v.y, 0.f);
      float v2 = fmaxf(hacc[colt][2] + b1v.z, 0.f);
      float v3 = fmaxf(hacc[colt][3] + b1v.w, 0.f);
      P01[colt] = packh2(v0, v1);
      P23[colt] = packh2(v2, v3);
    }
    __syncthreads();  // W2 staged

    // ---- stage 2: quad-permute hmid into B-frags, multiply with W2 from LDS ----
#pragma unroll
    for (int ktl = 0; ktl < 2; ++ktl) {
      half8 bh;
      {
        union { u32 d[4]; half8 s; } uh;
        int c0 = 2 * ktl, c1 = 2 * ktl + 1;
        u32 a0, a1;
        a0 = (u32)__shfl((int)P01[c0], srcA); a1 = (u32)__shfl((int)P01[c1], srcA);
        uh.d[0] = sel ? a1 : a0;
        a0 = (u32)__shfl((int)P23[c0], srcA); a1 = (u32)__shfl((int)P23[c1], srcA);
        uh.d[1] = sel ? a1 : a0;
        a0 = (u32)__shfl((int)P01[c0], srcB); a1 = (u32)__shfl((int)P01[c1], srcB);
        uh.d[2] = sel ? a1 : a0;
        a0 = (u32)__shfl((int)P23[c0], srcB); a1 = (u32)__shfl((int)P23[c1], srcB);
        uh.d[3] = sel ? a1 : a0;
        bh = uh.s;
      }
#pragma unroll
      for (int nt = 0; nt < 8; ++nt) {
        half8 wh = *(const half8*)&Ws[(ktl * 8 + nt) * 512 + lane * 8];
        oacc[nt] = __builtin_amdgcn_mfma_f32_16x16x32_f16(wh, bh, oacc[nt], 0, 0, 0);
      }
    }
  }

  // ---- epilogue: +b2, packed f16 store (8B), BN partials into slot ----
  const int node = n0 + l15;
#pragma unroll
  for (int nt = 0; nt < 8; ++nt) {
    int ocb = nt * 16 + q * 4;  // 4 consecutive out cols per lane
    float4 b2v = ld4(b2g + ocb);
    f32x4 s = (f32x4){0.f, 0.f, 0.f, 0.f};
    f32x4 s2 = (f32x4){0.f, 0.f, 0.f, 0.f};
    if (node < NN) {
      float v0 = oacc[nt][0] + b2v.x;
      float v1 = oacc[nt][1] + b2v.y;
      float v2 = oacc[nt][2] + b2v.z;
      float v3 = oacc[nt][3] + b2v.w;
      u64 pk = (u64)packh2(v0, v1) | ((u64)packh2(v2, v3) << 32);
      *(u64*)(hpre + (size_t)node * EMB + ocb) = pk;
      s[0] = v0; s[1] = v1; s[2] = v2; s[3] = v3;
      s2[0] = v0 * v0; s2[1] = v1 * v1; s2[2] = v2 * v2; s2[3] = v3 * v3;
    }
#pragma unroll
    for (int d = 1; d < 16; d <<= 1) {
#pragma unroll
      for (int r = 0; r < 4; ++r) {
        s[r] += __shfl_xor(s[r], d);
        s2[r] += __shfl_xor(s2[r], d);
      }
    }
    if (l15 == 0) {
#pragma unroll
      for (int r = 0; r < 4; ++r) {
        atomicAdd(&sums[ocb + r], s[r]);
        atomicAdd(&sums[128 + ocb + r], s2[r]);
      }
    }
  }
}

// ---------------- stats: reduce 32 slots -> scale/shift (sc, sh) ----------------
__global__ void stats_kernel(const float* __restrict__ slots,
                             const float* __restrict__ gamma,
                             const float* __restrict__ beta,
                             float* __restrict__ scsh) {
  int f = threadIdx.x;  // 128
  float s = 0.f, s2 = 0.f;
#pragma unroll 8
  for (int k = 0; k < 32; ++k) {
    s += slots[k * 256 + f];
    s2 += slots[k * 256 + 128 + f];
  }
  float mean = s * (1.0f / NN);
  float var = s2 * (1.0f / NN) - mean * mean;  // biased
  float sc = gamma[f] * rsqrtf(var + 1e-5f);
  scsh[f] = sc;
  scsh[128 + f] = beta[f] - mean * sc;
}

// ---------------- final output: out = hpre*sc + sh (f32, no relu) ----------------
__global__ __launch_bounds__(256) void out_kernel(
    const _Float16* __restrict__ hpre, const float* __restrict__ scsh,
    float* __restrict__ out) {
  int tid = blockIdx.x * blockDim.x + threadIdx.x;
  int n = tid >> 4;
  if (n >= NN) return;
  int kc = tid & 15;
  ulonglong2 raw = *(const ulonglong2*)(hpre + (size_t)n * EMB + kc * 8);
  _Float16* hr = (_Float16*)&raw;
  float4 sa = ld4(scsh + kc * 8), sb = ld4(scsh + kc * 8 + 4);
  float4 ha = ld4(scsh + 128 + kc * 8), hbv = ld4(scsh + 128 + kc * 8 + 4);
  float scv[8] = {sa.x, sa.y, sa.z, sa.w, sb.x, sb.y, sb.z, sb.w};
  float shv[8] = {ha.x, ha.y, ha.z, ha.w, hbv.x, hbv.y, hbv.z, hbv.w};
  float v[8];
#pragma unroll
  for (int j = 0; j < 8; ++j) v[j] = (float)hr[j] * scv[j] + shv[j];
  float* d = out + (size_t)n * EMB + kc * 8;
  *(float4*)d = make_float4(v[0], v[1], v[2], v[3]);
  *(float4*)(d + 4) = make_float4(v[4], v[5], v[6], v[7]);
}

// ---------------- launch ----------------
extern "C" void kernel_launch(void* const* d_in, const int* in_sizes, int n_in,
                              void* d_out, int out_size, void* d_ws, size_t ws_size,
                              hipStream_t stream) {
  const int* x = (const int*)d_in[0];
  const int* ei = (const int*)d_in[1];
  const int* ea = (const int*)d_in[2];
  const float* x_emb1 = (const float*)d_in[3];
  const float* x_emb2 = (const float*)d_in[4];
  const float* ee1 = (const float*)d_in[5];
  const float* ee2 = (const float*)d_in[6];
  const float* W1 = (const float*)d_in[7];
  const float* b1 = (const float*)d_in[8];
  const float* W2 = (const float*)d_in[9];
  const float* b2 = (const float*)d_in[10];
  const float* eps = (const float*)d_in[11];
  const float* gamma = (const float*)d_in[12];
  const float* beta = (const float*)d_in[13];
  float* out = (float*)d_out;

  // workspace layout (16B-aligned sections)
  float* slots = (float*)d_ws;                  // 5*32*256 BN partial slots
  float* scsh = slots + 5 * 32 * 256;           // 5*256 scale/shift
  _Float16* hpre = (_Float16*)(scsh + 5 * 256); // NN*128 f16
  _Float16* Af = hpre + (size_t)NN * EMB;       // NPAD*128 f16
  _Float16* hb = Af + (size_t)NPAD * EMB;       // NN*128 f16
  _Float16* W1f = hb + (size_t)NN * EMB;        // 5*32768 f16
  _Float16* W2f = W1f + 5 * 32768;              // 5*32768 f16
  _Float16* cbh = W2f + 5 * 32768;              // 5*15*128 f16 combos
  int* deg = (int*)(cbh + 5 * 15 * 128 + 64);   // NN (pad to 16B boundary)
  int* off = deg + NN;                          // NN+1
  int* csr = off + NN + 1;                      // NE
  int* bsum = csr + NE;                         // 128
  int* gbins = bsum + 128;                      // 64 degree-bin starts
  int* perm = gbins + 64;                       // NN degree-sorted node order

  const int NB_SCAN = (NN + 1023) / 1024;

  // one-time per launch: CSR + degree-sort + combo tables + frag-ordered f16 weights
  hipMemsetAsync(deg, 0, NN * sizeof(int), stream);
  hipMemsetAsync(gbins, 0, 64 * sizeof(int), stream);
  hipMemsetAsync(slots, 0, 5 * 32 * 256 * sizeof(float), stream);
  hist_kernel<<<(NE + 255) / 256, 256, 0, stream>>>(ei, deg);
  dhist_kernel<<<(NN + 255) / 256, 256, 0, stream>>>(deg, gbins);
  dscan_kernel<<<1, 64, 0, stream>>>(gbins);
  dscatter_kernel<<<(NN + 255) / 256, 256, 0, stream>>>(deg, gbins, perm);
  scan1_kernel<<<NB_SCAN, 256, 0, stream>>>(deg, off, bsum);
  scan2_kernel<<<1, 64, 0, stream>>>(bsum, off, NB_SCAN);
  scan3_kernel<<<(NN + 255) / 256, 256, 0, stream>>>(off, bsum);
  hipMemsetAsync(deg, 0, NN * sizeof(int), stream);
  scatter_kernel<<<(NE + 255) / 256, 256, 0, stream>>>(ei, ea, off, deg, csr);
  combo_kernel<<<(5 * 15 * 128 + 255) / 256, 256, 0, stream>>>(ee1, ee2, cbh);
  prep_w_kernel<<<160, 256, 0, stream>>>(W1, W2, W1f, W2f);
  node_init_kernel<<<NN * 16 / 256 + 1, 256, 0, stream>>>(x, x_emb1, x_emb2, hb);

  const int NBLK = NPAD / 64;  // 1564 blocks x 4 waves (16 nodes each)
  for (int i = 0; i < 5; ++i) {
    if (i == 0)
      agg_kernel<false><<<NPAD * 16 / 256, 256, 0, stream>>>(
          hb, nullptr, off, csr, cbh + (size_t)i * 15 * EMB, eps + i, perm, Af);
    else
      agg_kernel<true><<<NPAD * 16 / 256, 256, 0, stream>>>(
          hpre, scsh + (size_t)(i - 1) * 256, off, csr,
          cbh + (size_t)i * 15 * EMB, eps + i, perm, Af);
    mlp_kernel<<<NBLK, 256, 0, stream>>>(
        Af, W1f + (size_t)i * 32768, W2f + (size_t)i * 32768,
        b1 + (size_t)i * 256, b2 + (size_t)i * 128, hpre,
        slots + (size_t)i * 32 * 256);
    stats_kernel<<<1, 128, 0, stream>>>(slots + (size_t)i * 32 * 256,
                                        gamma + (size_t)i * EMB,
                                        beta + (size_t)i * EMB,
                                        scsh + (size_t)i * 256);
  }
  out_kernel<<<NN * 16 / 256 + 1, 256, 0, stream>>>(hpre, scsh + 4 * 256, out);
}